// Round 19
// baseline (427.496 us; speedup 1.0000x reference)
//
#include <hip/hip_runtime.h>
#include <math.h>

typedef __attribute__((ext_vector_type(8))) _Float16 half8;
typedef __attribute__((ext_vector_type(4))) float f32x4;
typedef __attribute__((ext_vector_type(4))) unsigned int u32x4;

namespace {
constexpr int NS = 32000, PAD = 200, NT = 201, TOUT = 192, NMEL = 128;
constexpr int PW_STRIDE = 236;                 // u16; 472B row stride -> 2-way-max LDS banks
constexpr int BAS_NT = 28;                     // DFT basis: K=416 (13x32), N=448 (cols 0..401 live)
constexpr int BAS_ELEMS = 13 * 28 * 64 * 8;    // 186368 u16
constexpr int FB_ELEMS  = 7 * 8 * 64 * 8;      // 28672 u16
constexpr int OUT_ROW_U16 = TOUT * NMEL * 2;   // 49152 u16 per out row
constexpr int MEL_OFF_U16 = OUT_ROW_U16 - NT * NMEL;  // mel fp16 packed in row tail
}

// audio-LDS XOR swizzle (elem bits [4:3] ^= bits [8:7]); 8-elem chunks stay contiguous.
__device__ __forceinline__ int swz(int e) { return e ^ (((e >> 7) & 3) << 3); }
__device__ __forceinline__ unsigned short f2h(float f) {
  _Float16 h = (_Float16)f; return __builtin_bit_cast(unsigned short, h);
}
__device__ __forceinline__ float h2f(unsigned short u) {
  return (float)__builtin_bit_cast(_Float16, u);
}

// ws tables, fp16, MFMA fragment layout (proven R4-R18):
//  [0, BAS_ELEMS): DFT basis frag[ks][nt][lane][j]: k=ks*32+(lane>>4)*8+j, col=nt*16+(lane&15)
//                  col even -> win[k]*cos(2*pi*bin*k/400), odd -> sin; bin=col/2; cols>=402 zero
//  [BAS_ELEMS, +FB_ELEMS): mel fb frag[ks][nt][lane][j]: k=freq bin (0 for k>200), col=mel
//  fb computed in fp32 (R3-proven: identical absmax 0.03125) -- no double transcendentals.
__global__ void setup_tables(unsigned short* __restrict__ ws) {
  int idx = blockIdx.x * 256 + threadIdx.x;
  if (idx < BAS_ELEMS) {
    int j = idx & 7, lane = (idx >> 3) & 63, rest = idx >> 9;
    int nt = rest % BAS_NT, ks = rest / BAS_NT;
    int k   = ks * 32 + ((lane >> 4) << 3) + j;
    int col = nt * 16 + (lane & 15);
    float v = 0.f;
    if (k < 400 && col < 402) {
      int bin = col >> 1;
      int mm  = (k * bin) % 400;
      float th = (float)mm * 0.015707963267948967f;   // 2*pi/400
      float tr = (col & 1) ? sinf(th) : cosf(th);
      float wn = 0.5f * (1.0f - cosf((float)k * 0.015707963267948967f));
      v = wn * tr;
    }
    ws[idx] = f2h(v);
  } else if (idx < BAS_ELEMS + FB_ELEMS) {
    int i2 = idx - BAS_ELEMS;
    int j = i2 & 7, lane = (i2 >> 3) & 63, rest = i2 >> 9;
    int nt = rest % 8, ks = rest / 8;
    int k   = ks * 32 + ((lane >> 4) << 3) + j;       // freq bin
    int mel = nt * 16 + (lane & 15);
    float v = 0.f;
    if (k <= 200) {
      float mhi = 2595.0f * log10f(1.0f + 8000.0f / 700.0f);
      float l2t = 3.3219280948873623f;                // log2(10)
      float ml = mhi * (float)mel       / 129.0f;
      float mc = mhi * (float)(mel + 1) / 129.0f;
      float mr = mhi * (float)(mel + 2) / 129.0f;
      float fl = 700.0f * (exp2f(ml / 2595.0f * l2t) - 1.0f);
      float fc = 700.0f * (exp2f(mc / 2595.0f * l2t) - 1.0f);
      float fr = 700.0f * (exp2f(mr / 2595.0f * l2t) - 1.0f);
      float f  = 40.0f * (float)k;
      float wv = fminf((f - fl) / (fc - fl), (fr - f) / (fr - fc));
      v = fmaxf(0.0f, wv);
    }
    ws[idx] = f2h(v);
  }
}

// ---- Kernel A: DFT -> power -> mel. Per-ks Bf[7] batch prefetch (7 L2 loads in
// flight, drained by 21 MFMAs) + setprio(1) around the MFMA cluster (T5: independent
// blocks at different phases on one CU). MT=3: strips s=0..3. MT=1: s=4 (frames 192..200).
template <int MT>
__global__ __launch_bounds__(256) __attribute__((amdgpu_waves_per_eu(3)))
void dft_mel_kernel(const float* __restrict__ audio, const unsigned short* __restrict__ ws,
                    unsigned short* __restrict__ outu)
{
  constexpr int AU = (MT == 3) ? 7936 : 2816;         // staged u16 elems
  __shared__ unsigned short au[AU];
  __shared__ unsigned short pw16[MT * 16 * PW_STRIDE];
  const int tid = threadIdx.x;
  const int bid = blockIdx.x;
  const int r  = (MT == 3) ? (bid >> 2) : bid;
  const int t0 = (MT == 3) ? ((bid & 3) * 48) : 192;
  const float* __restrict__ ab = audio + (size_t)r * NS;
  const int g0 = t0 * 160 - PAD;

  // phase 1: stage audio fp16 (reflect pad), vectorized: 2x float4 -> half8 -> b128 write
  {
    constexpr int nchunk = AU / 8;
    #pragma unroll 4
    for (int ci = tid; ci < nchunk; ci += 256) {
      half8 hv;
      int gbase = g0 + ci * 8;
      if (gbase >= 0 && gbase + 7 < NS) {             // aligned fast path (g0 % 8 == 0)
        const float4* p = (const float4*)(ab + gbase);
        float4 x0 = p[0], x1 = p[1];
        hv[0] = (_Float16)x0.x; hv[1] = (_Float16)x0.y;
        hv[2] = (_Float16)x0.z; hv[3] = (_Float16)x0.w;
        hv[4] = (_Float16)x1.x; hv[5] = (_Float16)x1.y;
        hv[6] = (_Float16)x1.z; hv[7] = (_Float16)x1.w;
      } else {                                        // reflect edges, scalar
        #pragma unroll
        for (int j = 0; j < 8; ++j) {
          int g = gbase + j;
          if (g < 0) g = -g;
          if (g >= NS) g = 2 * NS - 2 - g;
          hv[j] = (_Float16)ab[g];
        }
      }
      *(half8*)(au + swz(ci * 8)) = hv;
    }
  }
  __syncthreads();

  const int w = tid >> 6, lane = tid & 63, lr = lane & 15, lg = lane >> 4;

  // phase 2: DFT via MFMA; per-ks Bf[7]+Af[MT] batch then 7xMT MFMAs under setprio(1)
  f32x4 acc[MT][7];
  #pragma unroll
  for (int mm = 0; mm < MT; ++mm)
    #pragma unroll
    for (int n = 0; n < 7; ++n) acc[mm][n] = (f32x4){0.f, 0.f, 0.f, 0.f};
  {
    const int laneA = lr * 160 + lg * 8;
    const unsigned short* bptr = ws + ((size_t)(w * 7 * 64 + lane)) * 8;
    for (int ks = 0; ks < 13; ++ks) {
      half8 Bf[7];
      #pragma unroll
      for (int n = 0; n < 7; ++n) Bf[n] = *(const half8*)(bptr + n * 512);
      half8 Af[MT];
      #pragma unroll
      for (int mm = 0; mm < MT; ++mm)
        Af[mm] = *(const half8*)(au + swz(mm * 2560 + ks * 32 + laneA));
      __builtin_amdgcn_s_setprio(1);
      #pragma unroll
      for (int n = 0; n < 7; ++n)
        #pragma unroll
        for (int mm = 0; mm < MT; ++mm)
          acc[mm][n] = __builtin_amdgcn_mfma_f32_16x16x32_f16(Af[mm], Bf[n], acc[mm][n], 0, 0, 0);
      __builtin_amdgcn_s_setprio(0);
      bptr += BAS_NT * 512;
    }
  }
  __syncthreads();   // all audio reads done

  // phase 3: power = re^2 + im^2 via DPP quad-perm; all lanes write.
  // Even lane (bin=gcol/2) writes rows j=0,1; odd lane writes j=2,3 of the same bin.
  // Bins 201..223 get zeros automatically (basis cols >= 402 are zero).
  #pragma unroll
  for (int mm = 0; mm < MT; ++mm) {
    #pragma unroll
    for (int n = 0; n < 7; ++n) {
      int gcol = (w * 7 + n) * 16 + lr;
      int bin  = gcol >> 1;
      float p[4];
      #pragma unroll
      for (int j = 0; j < 4; ++j) {
        float v = acc[mm][n][j];
        int iv = __builtin_bit_cast(int, v);
        float q = __builtin_bit_cast(float,
            __builtin_amdgcn_mov_dpp(iv, 0xB1, 0xF, 0xF, true));  // quad_perm [1,0,3,2]
        p[j] = fmaf(v, v, q * q);
      }
      bool odd = (lr & 1);
      int rowb = mm * 16 + lg * 4 + (odd ? 2 : 0);
      pw16[rowb * PW_STRIDE + bin]       = f2h(odd ? p[2] : p[0]);
      pw16[(rowb + 1) * PW_STRIDE + bin] = f2h(odd ? p[3] : p[1]);
    }
  }
  __syncthreads();

  // phase 4: mel = power x fb (MFMA); fb fragments hoisted, power reads shared across nt
  {
    half8 Fb[2][7];
    const unsigned short* fbase = ws + BAS_ELEMS + (size_t)lane * 8;
    #pragma unroll
    for (int nt = 0; nt < 2; ++nt)
      #pragma unroll
      for (int ks = 0; ks < 7; ++ks)
        Fb[nt][ks] = *(const half8*)(fbase + ((size_t)(ks * 8 + 2 * w + nt)) * 512);
    unsigned short* __restrict__ outrow = outu + (size_t)r * OUT_ROW_U16 + MEL_OFF_U16;
    #pragma unroll
    for (int mt = 0; mt < MT; ++mt) {
      half8 Pa[7];
      const unsigned short* psrc = pw16 + (mt * 16 + lr) * PW_STRIDE + lg * 8;
      #pragma unroll
      for (int ks = 0; ks < 7; ++ks) Pa[ks] = *(const half8*)(psrc + ks * 32);
      #pragma unroll
      for (int nt = 0; nt < 2; ++nt) {
        f32x4 a2 = (f32x4){0.f, 0.f, 0.f, 0.f};
        #pragma unroll
        for (int ks = 0; ks < 7; ++ks)
          a2 = __builtin_amdgcn_mfma_f32_16x16x32_f16(Pa[ks], Fb[nt][ks], a2, 0, 0, 0);
        int gm = (2 * w + nt) * 16 + lr;
        #pragma unroll
        for (int j = 0; j < 4; ++j) {
          int t = t0 + mt * 16 + lg * 4 + j;
          if (MT == 3 || t < NT)
            outrow[t * NMEL + gm] = f2h(a2[j]);
        }
      }
    }
  }
}

// ---- Kernel B: per (row, mel-half): 16-chunk parallel PCEN scan + resize ----
__global__ __launch_bounds__(1024)
void pcen_resize_kernel(unsigned short* __restrict__ outu)
{
  __shared__ unsigned short mel[NT * 64];   // 25728 B, pcen fp16 in-place after scan
  __shared__ float carry[16][64];
  __shared__ float minb[16][64];
  const int tid = threadIdx.x;
  const int bid = blockIdx.x;
  const int r = bid >> 1, h = bid & 1;
  const unsigned short* src = outu + (size_t)r * OUT_ROW_U16 + MEL_OFF_U16 + h * 64;
  for (int i = tid; i < NT * 8; i += 1024) {         // 201 t-rows x 8 chunks of 8 u16
    int t = i >> 3, cc = i & 7;
    *(u32x4*)(mel + t * 64 + cc * 8) = *(const u32x4*)(src + t * 128 + cc * 8);
  }
  __syncthreads();

  const int m = tid & 63, c = tid >> 6;              // 16 chunks: 6, 13 x 15
  const int t0  = (c == 0) ? 0 : (6 + 13 * (c - 1));
  const int len = (c == 0) ? 6 : 13;

  // pass 1: chunk-local EMA endpoint (zero incoming state)
  float M = 0.f;
  for (int t = t0; t < t0 + len; ++t) {
    float e = h2f(mel[t * 64 + m]);
    M = (t == 0) ? e : fmaf(0.96f, M, 0.04f * e);
  }
  carry[c][m] = M;
  __syncthreads();
  if (c == 0) {
    float a13 = exp2f(13.0f * log2f(0.96f));         // 0.96^13
    float acc = carry[0][m];                          // chunk 0 endpoint (len 6)
    minb[1][m] = acc;
    #pragma unroll
    for (int cc = 2; cc < 16; ++cc) {
      acc = fmaf(a13, acc, carry[cc - 1][m]);
      minb[cc][m] = acc;
    }
  }
  __syncthreads();

  // pass 2: recompute with incoming prefix, write pcen fp16 in-place
  float Min = (c == 0) ? 0.f : minb[c][m];
  float wf = 1.f, Mloc = 0.f;
  for (int t = t0; t < t0 + len; ++t) {
    float e = h2f(mel[t * 64 + m]);
    Mloc = (t == 0) ? e : fmaf(0.96f, Mloc, 0.04f * e);
    wf *= 0.96f;
    float Mt = fmaf(wf, Min, Mloc);
    float dn = exp2f(0.8f * log2f(1e-8f + Mt));      // (1e-8+M)^0.8
    float pc = sqrtf(e / dn + 2.0f) - 1.41421356237309515f;
    mel[t * 64 + m] = f2h(pc);                       // own cell, read above
  }
  __syncthreads();

  // resize 201 -> 192 (time axis), antialiased triangle, 16-way t-parallel
  float* __restrict__ ob = (float*)outu + (size_t)r * TOUT * NMEL + h * 64;
  const float INVS = 201.0f / 192.0f;
  for (int i = c; i < TOUT; i += 16) {
    float ct = ((float)i + 0.5f) * INVS - 0.5f;
    int jlo = (int)ceilf(ct - INVS);
    int jhi = (int)floorf(ct + INVS);
    if (jlo < 0) jlo = 0;
    if (jhi > NT - 1) jhi = NT - 1;
    float wsum = 0.f, val = 0.f;
    for (int j = jlo; j <= jhi; ++j) {
      float wv = 1.0f - fabsf((float)j - ct) / INVS;
      if (wv > 0.f) { wsum += wv; val = fmaf(wv, h2f(mel[j * 64 + m]), val); }
    }
    ob[(size_t)i * NMEL + m] = val / wsum;
  }
}

extern "C" void kernel_launch(void* const* d_in, const int* in_sizes, int n_in,
                              void* d_out, int out_size, void* d_ws, size_t ws_size,
                              hipStream_t stream) {
  (void)in_sizes; (void)n_in; (void)out_size; (void)ws_size;
  unsigned short* ws = (unsigned short*)d_ws;
  setup_tables<<<(BAS_ELEMS + FB_ELEMS + 255) / 256, 256, 0, stream>>>(ws);
  dft_mel_kernel<3><<<2048 * 4, 256, 0, stream>>>((const float*)d_in[0], ws,
                                                  (unsigned short*)d_out);
  dft_mel_kernel<1><<<2048, 256, 0, stream>>>((const float*)d_in[0], ws,
                                              (unsigned short*)d_out);
  pcen_resize_kernel<<<4096, 1024, 0, stream>>>((unsigned short*)d_out);
}

// Round 20
// 373.273 us; speedup vs baseline: 1.1453x; 1.1453x over previous
//
#include <hip/hip_runtime.h>
#include <math.h>

typedef __attribute__((ext_vector_type(8))) _Float16 half8;
typedef __attribute__((ext_vector_type(4))) float f32x4;
typedef __attribute__((ext_vector_type(4))) unsigned int u32x4;

namespace {
constexpr int NS = 32000, PAD = 200, NT = 201, TOUT = 192, NMEL = 128;
constexpr int PW_STRIDE = 236;                 // u16; 472B row stride -> 2-way-max LDS banks
constexpr int BAS_NT = 28;                     // DFT basis: K=416 (13x32), N=448 (cols 0..401 live)
constexpr int BAS_ELEMS = 13 * 28 * 64 * 8;    // 186368 u16
constexpr int FB_ELEMS  = 7 * 8 * 64 * 8;      // 28672 u16
constexpr int OUT_ROW_U16 = TOUT * NMEL * 2;   // 49152 u16 per out row
constexpr int MEL_OFF_U16 = OUT_ROW_U16 - NT * NMEL;  // mel fp16 packed in row tail
}

// audio-LDS XOR swizzle (elem bits [4:3] ^= bits [8:7]); 8-elem chunks stay contiguous.
__device__ __forceinline__ int swz(int e) { return e ^ (((e >> 7) & 3) << 3); }
__device__ __forceinline__ unsigned short f2h(float f) {
  _Float16 h = (_Float16)f; return __builtin_bit_cast(unsigned short, h);
}
__device__ __forceinline__ float h2f(unsigned short u) {
  return (float)__builtin_bit_cast(_Float16, u);
}

// ws tables, fp16, MFMA fragment layout (proven R4-R19); fb in fp32 math (R19, absmax-identical).
__global__ void setup_tables(unsigned short* __restrict__ ws) {
  int idx = blockIdx.x * 256 + threadIdx.x;
  if (idx < BAS_ELEMS) {
    int j = idx & 7, lane = (idx >> 3) & 63, rest = idx >> 9;
    int nt = rest % BAS_NT, ks = rest / BAS_NT;
    int k   = ks * 32 + ((lane >> 4) << 3) + j;
    int col = nt * 16 + (lane & 15);
    float v = 0.f;
    if (k < 400 && col < 402) {
      int bin = col >> 1;
      int mm  = (k * bin) % 400;
      float th = (float)mm * 0.015707963267948967f;   // 2*pi/400
      float tr = (col & 1) ? sinf(th) : cosf(th);
      float wn = 0.5f * (1.0f - cosf((float)k * 0.015707963267948967f));
      v = wn * tr;
    }
    ws[idx] = f2h(v);
  } else if (idx < BAS_ELEMS + FB_ELEMS) {
    int i2 = idx - BAS_ELEMS;
    int j = i2 & 7, lane = (i2 >> 3) & 63, rest = i2 >> 9;
    int nt = rest % 8, ks = rest / 8;
    int k   = ks * 32 + ((lane >> 4) << 3) + j;       // freq bin
    int mel = nt * 16 + (lane & 15);
    float v = 0.f;
    if (k <= 200) {
      float mhi = 2595.0f * log10f(1.0f + 8000.0f / 700.0f);
      float l2t = 3.3219280948873623f;                // log2(10)
      float ml = mhi * (float)mel       / 129.0f;
      float mc = mhi * (float)(mel + 1) / 129.0f;
      float mr = mhi * (float)(mel + 2) / 129.0f;
      float fl = 700.0f * (exp2f(ml / 2595.0f * l2t) - 1.0f);
      float fc = 700.0f * (exp2f(mc / 2595.0f * l2t) - 1.0f);
      float fr = 700.0f * (exp2f(mr / 2595.0f * l2t) - 1.0f);
      float f  = 40.0f * (float)k;
      float wv = fminf((f - fl) / (fc - fl), (fr - f) / (fr - fc));
      v = fmaxf(0.0f, wv);
    }
    ws[idx] = f2h(v);
  }
}

// ---- Kernel A (R14/R18 exact body, proven 258 us): DFT -> power -> mel ----
template <int MT>
__global__ __launch_bounds__(256) __attribute__((amdgpu_waves_per_eu(3)))
void dft_mel_kernel(const float* __restrict__ audio, const unsigned short* __restrict__ ws,
                    unsigned short* __restrict__ outu)
{
  constexpr int AU = (MT == 3) ? 7936 : 2816;         // staged u16 elems
  __shared__ unsigned short au[AU];
  __shared__ unsigned short pw16[MT * 16 * PW_STRIDE];
  const int tid = threadIdx.x;
  const int bid = blockIdx.x;
  const int r  = (MT == 3) ? (bid >> 2) : bid;
  const int t0 = (MT == 3) ? ((bid & 3) * 48) : 192;
  const float* __restrict__ ab = audio + (size_t)r * NS;
  const int g0 = t0 * 160 - PAD;

  // phase 1: stage audio fp16 (reflect pad), vectorized: 2x float4 -> half8 -> b128 write
  {
    constexpr int nchunk = AU / 8;
    #pragma unroll 4
    for (int ci = tid; ci < nchunk; ci += 256) {
      half8 hv;
      int gbase = g0 + ci * 8;
      if (gbase >= 0 && gbase + 7 < NS) {             // aligned fast path (g0 % 8 == 0)
        const float4* p = (const float4*)(ab + gbase);
        float4 x0 = p[0], x1 = p[1];
        hv[0] = (_Float16)x0.x; hv[1] = (_Float16)x0.y;
        hv[2] = (_Float16)x0.z; hv[3] = (_Float16)x0.w;
        hv[4] = (_Float16)x1.x; hv[5] = (_Float16)x1.y;
        hv[6] = (_Float16)x1.z; hv[7] = (_Float16)x1.w;
      } else {                                        // reflect edges, scalar
        #pragma unroll
        for (int j = 0; j < 8; ++j) {
          int g = gbase + j;
          if (g < 0) g = -g;
          if (g >= NS) g = 2 * NS - 2 - g;
          hv[j] = (_Float16)ab[g];
        }
      }
      *(half8*)(au + swz(ci * 8)) = hv;
    }
  }
  __syncthreads();

  const int w = tid >> 6, lane = tid & 63, lr = lane & 15, lg = lane >> 4;

  // phase 2: DFT via MFMA; per-ks Bf[7]+Af[MT] batch then 7xMT MFMAs
  f32x4 acc[MT][7];
  #pragma unroll
  for (int mm = 0; mm < MT; ++mm)
    #pragma unroll
    for (int n = 0; n < 7; ++n) acc[mm][n] = (f32x4){0.f, 0.f, 0.f, 0.f};
  {
    const int laneA = lr * 160 + lg * 8;
    const unsigned short* bptr = ws + ((size_t)(w * 7 * 64 + lane)) * 8;
    for (int ks = 0; ks < 13; ++ks) {
      half8 Bf[7];
      #pragma unroll
      for (int n = 0; n < 7; ++n) Bf[n] = *(const half8*)(bptr + n * 512);
      half8 Af[MT];
      #pragma unroll
      for (int mm = 0; mm < MT; ++mm)
        Af[mm] = *(const half8*)(au + swz(mm * 2560 + ks * 32 + laneA));
      #pragma unroll
      for (int n = 0; n < 7; ++n)
        #pragma unroll
        for (int mm = 0; mm < MT; ++mm)
          acc[mm][n] = __builtin_amdgcn_mfma_f32_16x16x32_f16(Af[mm], Bf[n], acc[mm][n], 0, 0, 0);
      bptr += BAS_NT * 512;
    }
  }
  __syncthreads();   // all audio reads done

  // phase 3: power = re^2 + im^2 via DPP quad-perm; all lanes write.
  #pragma unroll
  for (int mm = 0; mm < MT; ++mm) {
    #pragma unroll
    for (int n = 0; n < 7; ++n) {
      int gcol = (w * 7 + n) * 16 + lr;
      int bin  = gcol >> 1;
      float p[4];
      #pragma unroll
      for (int j = 0; j < 4; ++j) {
        float v = acc[mm][n][j];
        int iv = __builtin_bit_cast(int, v);
        float q = __builtin_bit_cast(float,
            __builtin_amdgcn_mov_dpp(iv, 0xB1, 0xF, 0xF, true));  // quad_perm [1,0,3,2]
        p[j] = fmaf(v, v, q * q);
      }
      bool odd = (lr & 1);
      int rowb = mm * 16 + lg * 4 + (odd ? 2 : 0);
      pw16[rowb * PW_STRIDE + bin]       = f2h(odd ? p[2] : p[0]);
      pw16[(rowb + 1) * PW_STRIDE + bin] = f2h(odd ? p[3] : p[1]);
    }
  }
  __syncthreads();

  // phase 4: mel = power x fb (MFMA); fb fragments hoisted, power reads shared across nt
  {
    half8 Fb[2][7];
    const unsigned short* fbase = ws + BAS_ELEMS + (size_t)lane * 8;
    #pragma unroll
    for (int nt = 0; nt < 2; ++nt)
      #pragma unroll
      for (int ks = 0; ks < 7; ++ks)
        Fb[nt][ks] = *(const half8*)(fbase + ((size_t)(ks * 8 + 2 * w + nt)) * 512);
    unsigned short* __restrict__ outrow = outu + (size_t)r * OUT_ROW_U16 + MEL_OFF_U16;
    #pragma unroll
    for (int mt = 0; mt < MT; ++mt) {
      half8 Pa[7];
      const unsigned short* psrc = pw16 + (mt * 16 + lr) * PW_STRIDE + lg * 8;
      #pragma unroll
      for (int ks = 0; ks < 7; ++ks) Pa[ks] = *(const half8*)(psrc + ks * 32);
      #pragma unroll
      for (int nt = 0; nt < 2; ++nt) {
        f32x4 a2 = (f32x4){0.f, 0.f, 0.f, 0.f};
        #pragma unroll
        for (int ks = 0; ks < 7; ++ks)
          a2 = __builtin_amdgcn_mfma_f32_16x16x32_f16(Pa[ks], Fb[nt][ks], a2, 0, 0, 0);
        int gm = (2 * w + nt) * 16 + lr;
        #pragma unroll
        for (int j = 0; j < 4; ++j) {
          int t = t0 + mt * 16 + lg * 4 + j;
          if (MT == 3 || t < NT)
            outrow[t * NMEL + gm] = f2h(a2[j]);
        }
      }
    }
  }
}

// ---- Kernel B: 16-chunk parallel PCEN scan + resize with VECTORIZED float4 stores ----
__global__ __launch_bounds__(1024)
void pcen_resize_kernel(unsigned short* __restrict__ outu)
{
  __shared__ unsigned short mel[NT * 64];   // 25728 B, pcen fp16 in-place after scan
  __shared__ float carry[16][64];
  __shared__ float minb[16][64];
  const int tid = threadIdx.x;
  const int bid = blockIdx.x;
  const int r = bid >> 1, h = bid & 1;
  const unsigned short* src = outu + (size_t)r * OUT_ROW_U16 + MEL_OFF_U16 + h * 64;
  for (int i = tid; i < NT * 8; i += 1024) {         // 201 t-rows x 8 chunks of 8 u16
    int t = i >> 3, cc = i & 7;
    *(u32x4*)(mel + t * 64 + cc * 8) = *(const u32x4*)(src + t * 128 + cc * 8);
  }
  __syncthreads();

  const int m = tid & 63, c = tid >> 6;              // 16 chunks: 6, 13 x 15
  const int t0  = (c == 0) ? 0 : (6 + 13 * (c - 1));
  const int len = (c == 0) ? 6 : 13;

  // pass 1: chunk-local EMA endpoint (zero incoming state)
  float M = 0.f;
  for (int t = t0; t < t0 + len; ++t) {
    float e = h2f(mel[t * 64 + m]);
    M = (t == 0) ? e : fmaf(0.96f, M, 0.04f * e);
  }
  carry[c][m] = M;
  __syncthreads();
  if (c == 0) {
    float a13 = exp2f(13.0f * log2f(0.96f));         // 0.96^13
    float acc = carry[0][m];                          // chunk 0 endpoint (len 6)
    minb[1][m] = acc;
    #pragma unroll
    for (int cc = 2; cc < 16; ++cc) {
      acc = fmaf(a13, acc, carry[cc - 1][m]);
      minb[cc][m] = acc;
    }
  }
  __syncthreads();

  // pass 2: recompute with incoming prefix, write pcen fp16 in-place
  float Min = (c == 0) ? 0.f : minb[c][m];
  float wf = 1.f, Mloc = 0.f;
  for (int t = t0; t < t0 + len; ++t) {
    float e = h2f(mel[t * 64 + m]);
    Mloc = (t == 0) ? e : fmaf(0.96f, Mloc, 0.04f * e);
    wf *= 0.96f;
    float Mt = fmaf(wf, Min, Mloc);
    float dn = exp2f(0.8f * log2f(1e-8f + Mt));      // (1e-8+M)^0.8
    float pc = sqrtf(e / dn + 2.0f) - 1.41421356237309515f;
    mel[t * 64 + m] = f2h(pc);                       // own cell, read above
  }
  __syncthreads();

  // resize 201 -> 192 (time axis), antialiased triangle, float4 stores (16B/lane).
  // Thread -> (m4 = 4 consecutive mels, irow); 3 iterations of i; 1KB/wave-quad stores.
  float* __restrict__ ob = (float*)outu + (size_t)r * TOUT * NMEL + h * 64;
  const float INVS = 201.0f / 192.0f;
  const int m4 = (tid & 15) * 4;                     // mel offset within half
  const int ir = tid >> 4;                           // 0..63
  for (int i = ir; i < TOUT; i += 64) {
    float ct = ((float)i + 0.5f) * INVS - 0.5f;
    int jlo = (int)ceilf(ct - INVS);
    int jhi = (int)floorf(ct + INVS);
    if (jlo < 0) jlo = 0;
    if (jhi > NT - 1) jhi = NT - 1;
    float wsum = 0.f;
    float4 val = make_float4(0.f, 0.f, 0.f, 0.f);
    for (int j = jlo; j <= jhi; ++j) {
      float wv = 1.0f - fabsf((float)j - ct) / INVS;
      if (wv > 0.f) {
        wsum += wv;
        const unsigned short* mr = mel + j * 64 + m4;
        val.x = fmaf(wv, h2f(mr[0]), val.x);
        val.y = fmaf(wv, h2f(mr[1]), val.y);
        val.z = fmaf(wv, h2f(mr[2]), val.z);
        val.w = fmaf(wv, h2f(mr[3]), val.w);
      }
    }
    float inv = 1.0f / wsum;
    val.x *= inv; val.y *= inv; val.z *= inv; val.w *= inv;
    *(float4*)(ob + (size_t)i * NMEL + m4) = val;
  }
}

extern "C" void kernel_launch(void* const* d_in, const int* in_sizes, int n_in,
                              void* d_out, int out_size, void* d_ws, size_t ws_size,
                              hipStream_t stream) {
  (void)in_sizes; (void)n_in; (void)out_size; (void)ws_size;
  unsigned short* ws = (unsigned short*)d_ws;
  setup_tables<<<(BAS_ELEMS + FB_ELEMS + 255) / 256, 256, 0, stream>>>(ws);
  dft_mel_kernel<3><<<2048 * 4, 256, 0, stream>>>((const float*)d_in[0], ws,
                                                  (unsigned short*)d_out);
  dft_mel_kernel<1><<<2048, 256, 0, stream>>>((const float*)d_in[0], ws,
                                              (unsigned short*)d_out);
  pcen_resize_kernel<<<4096, 1024, 0, stream>>>((unsigned short*)d_out);
}